// Round 1
// baseline (733.731 us; speedup 1.0000x reference)
//
#include <hip/hip_runtime.h>

// Fused TP all-reduce + residual add + RMSNorm (DeepSeek pattern), fp32.
// hs: [TP, TOKENS, HIDDEN], residual: [TOKENS, HIDDEN], w: [HIDDEN]
// out: normed [TOKENS, HIDDEN] followed by residual_out [TOKENS, HIDDEN]

constexpr int TP      = 4;
constexpr int TOKENS  = 4096;
constexpr int HIDDEN  = 7168;
constexpr float EPS   = 1e-6f;

constexpr int BLOCK   = 256;
constexpr int VEC     = 4;                       // float4
constexpr int PER_T   = HIDDEN / (BLOCK * VEC);  // 7 float4 chunks per thread

static_assert(HIDDEN == BLOCK * VEC * PER_T, "exact tiling required");

__global__ __launch_bounds__(BLOCK)
void fused_allreduce_rmsnorm(const float* __restrict__ hs,
                             const float* __restrict__ residual,
                             const float* __restrict__ w,
                             float* __restrict__ normed,
                             float* __restrict__ res_out) {
    const int row = blockIdx.x;
    const int tid = threadIdx.x;

    const size_t row_off = (size_t)row * HIDDEN;
    const size_t plane4  = (size_t)TOKENS * HIDDEN / VEC;  // plane stride in float4

    const float4* __restrict__ h4 = (const float4*)(hs + row_off);
    const float4* __restrict__ r4 = (const float4*)(residual + row_off);
    float4* __restrict__ ro4 = (float4*)(res_out + row_off);
    float4* __restrict__ no4 = (float4*)(normed + row_off);
    const float4* __restrict__ w4 = (const float4*)w;

    float4 acc[PER_T];
    float sumsq = 0.f;

    #pragma unroll
    for (int i = 0; i < PER_T; ++i) {
        const int idx = tid + i * BLOCK;
        float4 a = h4[idx];
        float4 b = h4[idx + plane4];
        float4 c = h4[idx + 2 * plane4];
        float4 d = h4[idx + 3 * plane4];
        float4 r = r4[idx];
        float4 s;
        s.x = a.x + b.x + c.x + d.x + r.x;
        s.y = a.y + b.y + c.y + d.y + r.y;
        s.z = a.z + b.z + c.z + d.z + r.z;
        s.w = a.w + b.w + c.w + d.w + r.w;
        acc[i] = s;
        ro4[idx] = s;  // residual_out write, overlapped with next loads
        sumsq += s.x * s.x + s.y * s.y + s.z * s.z + s.w * s.w;
    }

    // Block reduction of sumsq: wave64 shuffle tree, then tiny LDS combine.
    #pragma unroll
    for (int off = 32; off > 0; off >>= 1)
        sumsq += __shfl_down(sumsq, off);

    __shared__ float wave_sum[BLOCK / 64];
    const int lane = tid & 63;
    const int wid  = tid >> 6;
    if (lane == 0) wave_sum[wid] = sumsq;
    __syncthreads();

    const float total = wave_sum[0] + wave_sum[1] + wave_sum[2] + wave_sum[3];
    const float scale = rsqrtf(total * (1.0f / HIDDEN) + EPS);

    #pragma unroll
    for (int i = 0; i < PER_T; ++i) {
        const int idx = tid + i * BLOCK;
        float4 g = w4[idx];
        float4 s = acc[i];
        float4 o;
        o.x = s.x * scale * g.x;
        o.y = s.y * scale * g.y;
        o.z = s.z * scale * g.z;
        o.w = s.w * scale * g.w;
        no4[idx] = o;
    }
}

extern "C" void kernel_launch(void* const* d_in, const int* in_sizes, int n_in,
                              void* d_out, int out_size, void* d_ws, size_t ws_size,
                              hipStream_t stream) {
    const float* hs       = (const float*)d_in[0];  // [TP, TOKENS, HIDDEN]
    const float* residual = (const float*)d_in[1];  // [TOKENS, HIDDEN]
    const float* w        = (const float*)d_in[2];  // [HIDDEN]

    float* normed  = (float*)d_out;                          // first output
    float* res_out = (float*)d_out + (size_t)TOKENS * HIDDEN; // second output

    dim3 grid(TOKENS);
    dim3 block(BLOCK);
    fused_allreduce_rmsnorm<<<grid, block, 0, stream>>>(hs, residual, w, normed, res_out);
}

// Round 2
// 704.980 us; speedup vs baseline: 1.0408x; 1.0408x over previous
//
#include <hip/hip_runtime.h>

// Fused TP all-reduce + residual add + RMSNorm (DeepSeek pattern), fp32.
// hs: [TP, TOKENS, HIDDEN], residual: [TOKENS, HIDDEN], w: [HIDDEN]
// out: normed [TOKENS, HIDDEN] followed by residual_out [TOKENS, HIDDEN]
//
// Pure streaming kernel: 822 MB mandatory HBM traffic, ~130 us floor @ 6.3 TB/s.
// Non-temporal hints on all streaming accesses; weight stays cached (28 KB, reused
// by all 4096 blocks).

constexpr int TP      = 4;
constexpr int TOKENS  = 4096;
constexpr int HIDDEN  = 7168;
constexpr float EPS   = 1e-6f;

constexpr int BLOCK   = 256;
constexpr int VEC     = 4;                       // float4
constexpr int PER_T   = HIDDEN / (BLOCK * VEC);  // 7 chunks per thread

static_assert(HIDDEN == BLOCK * VEC * PER_T, "exact tiling required");

typedef float f4 __attribute__((ext_vector_type(4)));

__global__ __launch_bounds__(BLOCK, 4)  // cap VGPR<=128 -> >=4 waves/EU resident
void fused_allreduce_rmsnorm(const float* __restrict__ hs,
                             const float* __restrict__ residual,
                             const float* __restrict__ w,
                             float* __restrict__ normed,
                             float* __restrict__ res_out) {
    const int row = blockIdx.x;
    const int tid = threadIdx.x;

    const size_t row_off = (size_t)row * HIDDEN;
    const size_t plane4  = (size_t)TOKENS * (HIDDEN / VEC);  // plane stride in f4

    const f4* __restrict__ h4 = (const f4*)(hs + row_off);
    const f4* __restrict__ r4 = (const f4*)(residual + row_off);
    f4* __restrict__ ro4 = (f4*)(res_out + row_off);
    f4* __restrict__ no4 = (f4*)(normed + row_off);
    const f4* __restrict__ w4 = (const f4*)w;

    f4 acc[PER_T];
    // 4 independent accumulators: break the serial FMA dependency chain.
    float sx = 0.f, sy = 0.f, sz = 0.f, sw = 0.f;

    #pragma unroll
    for (int i = 0; i < PER_T; ++i) {
        const size_t idx = (size_t)(tid + i * BLOCK);
        f4 a = __builtin_nontemporal_load(&h4[idx]);
        f4 b = __builtin_nontemporal_load(&h4[idx + plane4]);
        f4 c = __builtin_nontemporal_load(&h4[idx + 2 * plane4]);
        f4 d = __builtin_nontemporal_load(&h4[idx + 3 * plane4]);
        f4 r = __builtin_nontemporal_load(&r4[idx]);
        f4 s = a + b + c + d + r;
        acc[i] = s;
        __builtin_nontemporal_store(s, &ro4[idx]);  // residual_out
        sx += s.x * s.x;
        sy += s.y * s.y;
        sz += s.z * s.z;
        sw += s.w * s.w;
    }
    float sumsq = (sx + sy) + (sz + sw);

    // Wave64 shuffle reduction, then tiny LDS combine across the 4 waves.
    #pragma unroll
    for (int off = 32; off > 0; off >>= 1)
        sumsq += __shfl_down(sumsq, off);

    __shared__ float wave_sum[BLOCK / 64];
    if ((tid & 63) == 0) wave_sum[tid >> 6] = sumsq;
    __syncthreads();

    const float total = wave_sum[0] + wave_sum[1] + wave_sum[2] + wave_sum[3];
    const float scale = rsqrtf(total * (1.0f / HIDDEN) + EPS);

    #pragma unroll
    for (int i = 0; i < PER_T; ++i) {
        const size_t idx = (size_t)(tid + i * BLOCK);
        f4 g = w4[idx];          // cached: 28 KB, reused by every block
        f4 s = acc[i];
        f4 o = s * scale * g;
        __builtin_nontemporal_store(o, &no4[idx]);  // normed
    }
}

extern "C" void kernel_launch(void* const* d_in, const int* in_sizes, int n_in,
                              void* d_out, int out_size, void* d_ws, size_t ws_size,
                              hipStream_t stream) {
    const float* hs       = (const float*)d_in[0];  // [TP, TOKENS, HIDDEN]
    const float* residual = (const float*)d_in[1];  // [TOKENS, HIDDEN]
    const float* w        = (const float*)d_in[2];  // [HIDDEN]

    float* normed  = (float*)d_out;                           // output 0
    float* res_out = (float*)d_out + (size_t)TOKENS * HIDDEN; // output 1

    dim3 grid(TOKENS);
    dim3 block(BLOCK);
    fused_allreduce_rmsnorm<<<grid, block, 0, stream>>>(hs, residual, w, normed, res_out);
}